// Round 2
// baseline (108.256 us; speedup 1.0000x reference)
//
#include <hip/hip_runtime.h>
#include <cfloat>
#include <math.h>
#include <stdint.h>

// Match XLA-CPU f32 arithmetic exactly: no implicit contraction anywhere;
// FMA only where written explicitly (Eigen-gemm-style cross product).
#pragma clang fp contract(off)

__device__ __forceinline__ uint32_t monotone_key(float f) {
    uint32_t u = __float_as_uint(f);
    return (u & 0x80000000u) ? ~u : (u | 0x80000000u);
}

// One block = one tile of 1024 points. Phase 1: expand (L,3)->(L,4) stores +
// per-lane m_sq into LDS (packed 4/float4). Phase 2: per-wave argmin over its
// 256-point chunk, lane = receiver, coords re-read via wave-uniform loads
// (SMEM / L2-hot), m_sq via one broadcast ds_read_b128 per 4 points.
__global__ void __launch_bounds__(256) fused_kernel(
        const float* __restrict__ mesh, const float* __restrict__ recv,
        float* __restrict__ out, unsigned long long* __restrict__ ws,
        int L, int B) {
    __shared__ float4 msq_tile[256];
    __shared__ unsigned long long red[4][64];

    const int tid  = threadIdx.x;
    const int lane = tid & 63;
    const int wave = __builtin_amdgcn_readfirstlane(tid >> 6);  // uniform
    const int base = blockIdx.x << 10;   // 1024 points per block

    // receiver per lane (B == 64 == wave size)
    float rx = 0.f, ry = 0.f, rz = 0.f, rsq = 0.f;
    if (lane < B) {
        rx = recv[lane * 3 + 0];
        ry = recv[lane * 3 + 1];
        rz = recv[lane * 3 + 2];
        rsq = (rx * rx + ry * ry) + rz * rz;   // no FMA (pragma)
    }

    // ---- phase 1: expand + m_sq ----
    const int p0 = base + tid * 4;
    if (p0 + 3 < L) {
        const float4* __restrict__ m4 = (const float4*)(mesh + (size_t)p0 * 3);
        const float4 a = m4[0], b = m4[1], c = m4[2];
        float4* __restrict__ o4 = (float4*)(out + (size_t)p0 * 4);
        o4[0] = make_float4(a.x, a.y, a.z, 0.f);
        o4[1] = make_float4(a.w, b.x, b.y, 0.f);
        o4[2] = make_float4(b.z, b.w, c.x, 0.f);
        o4[3] = make_float4(c.y, c.z, c.w, 0.f);
        msq_tile[tid] = make_float4(
            (a.x * a.x + a.y * a.y) + a.z * a.z,   // matches jnp.sum(m*m): no FMA
            (a.w * a.w + b.x * b.x) + b.y * b.y,
            (b.z * b.z + b.w * b.w) + c.x * c.x,
            (c.y * c.y + c.z * c.z) + c.w * c.w);
    } else {
        float q[4];
        for (int k = 0; k < 4; ++k) {
            const int p = p0 + k;
            if (p < L) {
                float x = mesh[(size_t)p * 3 + 0];
                float y = mesh[(size_t)p * 3 + 1];
                float z = mesh[(size_t)p * 3 + 2];
                out[(size_t)p * 4 + 0] = x;
                out[(size_t)p * 4 + 1] = y;
                out[(size_t)p * 4 + 2] = z;
                out[(size_t)p * 4 + 3] = 0.f;
                q[k] = (x * x + y * y) + z * z;
            } else {
                q[k] = INFINITY;   // never selected
            }
        }
        msq_tile[tid] = make_float4(q[0], q[1], q[2], q[3]);
    }
    __syncthreads();

    // ---- phase 2: pair loop, wave handles points [wchunk, wchunk+256) ----
    float best = FLT_MAX;
    int   bidx = 0x7fffffff;
    const int wchunk = base + wave * 256;
    const float4* __restrict__ wp4 = (const float4*)(mesh + (size_t)wchunk * 3);

    if (wchunk + 256 <= L) {
        #pragma unroll 2
        for (int g = 0; g < 64; ++g) {
            const float4 mq = msq_tile[wave * 64 + g];   // b128 broadcast: 4 m_sq
            const float4 c0 = wp4[g * 3 + 0];  // x0 y0 z0 x1  (wave-uniform addr)
            const float4 c1 = wp4[g * 3 + 1];  // y1 z1 x2 y2
            const float4 c2 = wp4[g * 3 + 2];  // z2 x3 y3 z3
            const int gidx = wchunk + g * 4;
            { float cr = fmaf(rz, c0.z, fmaf(ry, c0.y, rx * c0.x));
              float d2 = fmaf(-2.0f, cr, mq.x) + rsq;
              if (d2 < best) { best = d2; bidx = gidx + 0; } }
            { float cr = fmaf(rz, c1.y, fmaf(ry, c1.x, rx * c0.w));
              float d2 = fmaf(-2.0f, cr, mq.y) + rsq;
              if (d2 < best) { best = d2; bidx = gidx + 1; } }
            { float cr = fmaf(rz, c2.x, fmaf(ry, c1.w, rx * c1.z));
              float d2 = fmaf(-2.0f, cr, mq.z) + rsq;
              if (d2 < best) { best = d2; bidx = gidx + 2; } }
            { float cr = fmaf(rz, c2.w, fmaf(ry, c2.z, rx * c2.y));
              float d2 = fmaf(-2.0f, cr, mq.w) + rsq;
              if (d2 < best) { best = d2; bidx = gidx + 3; } }
        }
    } else {
        for (int j = 0; j < 256; ++j) {
            const int p = wchunk + j;
            if (p >= L) break;
            const float x = mesh[(size_t)p * 3 + 0];
            const float y = mesh[(size_t)p * 3 + 1];
            const float z = mesh[(size_t)p * 3 + 2];
            const float4 mq = msq_tile[wave * 64 + (j >> 2)];
            const int s = j & 3;
            const float msq = s == 0 ? mq.x : (s == 1 ? mq.y : (s == 2 ? mq.z : mq.w));
            float cr = fmaf(rz, z, fmaf(ry, y, rx * x));
            float d2 = fmaf(-2.0f, cr, msq) + rsq;
            if (d2 < best) { best = d2; bidx = p; }   // strict <: first-idx ties
        }
    }

    // block reduce across the 4 waves, then one packed atomic per receiver
    unsigned long long key =
        ((unsigned long long)monotone_key(best) << 32) | (unsigned int)bidx;
    red[wave][lane] = key;
    __syncthreads();
    if (wave == 0 && lane < B) {
        unsigned long long k = red[0][lane];
        unsigned long long k1 = red[1][lane]; if (k1 < k) k = k1;
        unsigned long long k2 = red[2][lane]; if (k2 < k) k = k2;
        unsigned long long k3 = red[3][lane]; if (k3 < k) k = k3;
        atomicMin(&ws[lane], k);
    }
}

// scatter one-hot 1.0s and emit closest_points
__global__ void finalize_kernel(
        const float* __restrict__ mesh, const unsigned long long* __restrict__ ws,
        float* __restrict__ out, int L, int B) {
    const int r = threadIdx.x;
    if (r >= B) return;
    const int idx = (int)(ws[r] & 0xFFFFFFFFull);
    out[(size_t)idx * 4 + 3] = 1.0f;
    float* cp = out + (size_t)L * 4 + (size_t)r * 3;
    cp[0] = mesh[(size_t)idx * 3 + 0];
    cp[1] = mesh[(size_t)idx * 3 + 1];
    cp[2] = mesh[(size_t)idx * 3 + 2];
}

extern "C" void kernel_launch(void* const* d_in, const int* in_sizes, int n_in,
                              void* d_out, int out_size, void* d_ws, size_t ws_size,
                              hipStream_t stream) {
    const float* mesh = (const float*)d_in[0];
    const float* recv = (const float*)d_in[1];
    float* out = (float*)d_out;
    const int L = in_sizes[0] / 3;
    const int B = in_sizes[1] / 3;   // 64
    unsigned long long* ws = (unsigned long long*)d_ws;

    // init per-receiver packed (key|idx) mins to all-ones (max)
    hipMemsetAsync(ws, 0xFF, (size_t)B * sizeof(unsigned long long), stream);

    const int nblk = (L + 1023) / 1024;
    fused_kernel<<<nblk, 256, 0, stream>>>(mesh, recv, out, ws, L, B);

    finalize_kernel<<<1, 64, 0, stream>>>(mesh, ws, out, L, B);
}

// Round 3
// 70.207 us; speedup vs baseline: 1.5419x; 1.5419x over previous
//
#include <hip/hip_runtime.h>
#include <cfloat>
#include <math.h>
#include <stdint.h>

// Match XLA-CPU f32 arithmetic exactly: no implicit contraction anywhere;
// FMA only where written explicitly (Eigen-gemm-style cross product).
#pragma clang fp contract(off)

#define RPW 16    // receivers per block (quarter of B=64)
#define PPL 4     // points per lane per tile
#define NQ  256   // tile-phase blocks per receiver-quarter; grid = 4*NQ

__device__ __forceinline__ uint32_t monotone_key(float f) {
    uint32_t u = __float_as_uint(f);
    return (u & 0x80000000u) ? ~u : (u | 0x80000000u);
}

// force a wave-uniform float into an SGPR
__device__ __forceinline__ float rfl_f(float x) {
    return __uint_as_float((uint32_t)__builtin_amdgcn_readfirstlane((int)__float_as_uint(x)));
}

// lane = point; 16 receivers per block live in SGPRs -> inner loop is pure
// VALU (8 ops/pair-eval, 1 free SGPR operand per instr), no LDS/VMEM feed.
__global__ void __launch_bounds__(256, 4) fused_kernel(
        const float* __restrict__ mesh, const float* __restrict__ recv,
        float* __restrict__ out, unsigned long long* __restrict__ ws,
        int L, int B, int ntiles) {
    __shared__ unsigned long long lds1[256][RPW + 1];   // +1 pad: no bank conflicts
    __shared__ unsigned long long lds2[16][RPW + 1];

    const int tid  = threadIdx.x;
    const int lane = tid & 63;
    const int wave = tid >> 6;
    const int rq   = blockIdx.x / NQ;      // receiver quarter 0..3
    const int q0   = blockIdx.x % NQ;      // starting tile phase

    // ---- receiver set into SGPRs (once) ----
    float rx[RPW], ry[RPW], rz[RPW], rsq[RPW];
#pragma unroll
    for (int c = 0; c < RPW; ++c) {
        const int r = rq * RPW + c;
        float x = 0.f, y = 0.f, z = 0.f;
        if (r < B) {                       // uniform branch
            x = recv[r * 3 + 0];
            y = recv[r * 3 + 1];
            z = recv[r * 3 + 2];
        }
        rx[c]  = rfl_f(x);
        ry[c]  = rfl_f(y);
        rz[c]  = rfl_f(z);
        rsq[c] = rfl_f((x * x + y * y) + z * z);   // no FMA (pragma)
    }

    float best[RPW];
    int   bidx[RPW];
#pragma unroll
    for (int c = 0; c < RPW; ++c) { best[c] = FLT_MAX; bidx[c] = 0x7fffffff; }

    const bool writer = (rq == 0);         // exactly one quarter writes `out`

    for (int t = q0; t < ntiles; t += NQ) {
        const int p0 = (t << 10) + (wave << 8) + (lane << 2);   // lane's 4 points
        float xs[PPL], ys[PPL], zs[PPL], ms[PPL];
        if (p0 + PPL <= L) {
            const float4* __restrict__ m4 = (const float4*)(mesh + (size_t)p0 * 3);
            const float4 fa = m4[0], fb = m4[1], fc = m4[2];
            if (writer) {
                float4* __restrict__ o4 = (float4*)(out + (size_t)p0 * 4);
                o4[0] = make_float4(fa.x, fa.y, fa.z, 0.f);
                o4[1] = make_float4(fa.w, fb.x, fb.y, 0.f);
                o4[2] = make_float4(fb.z, fb.w, fc.x, 0.f);
                o4[3] = make_float4(fc.y, fc.z, fc.w, 0.f);
            }
            xs[0] = fa.x; ys[0] = fa.y; zs[0] = fa.z;
            xs[1] = fa.w; ys[1] = fb.x; zs[1] = fb.y;
            xs[2] = fb.z; ys[2] = fb.w; zs[2] = fc.x;
            xs[3] = fc.y; ys[3] = fc.z; zs[3] = fc.w;
#pragma unroll
            for (int j = 0; j < PPL; ++j)
                ms[j] = (xs[j] * xs[j] + ys[j] * ys[j]) + zs[j] * zs[j];  // matches jnp.sum(m*m)
        } else {
#pragma unroll
            for (int j = 0; j < PPL; ++j) {
                const int p = p0 + j;
                if (p < L) {
                    xs[j] = mesh[(size_t)p * 3 + 0];
                    ys[j] = mesh[(size_t)p * 3 + 1];
                    zs[j] = mesh[(size_t)p * 3 + 2];
                    ms[j] = (xs[j] * xs[j] + ys[j] * ys[j]) + zs[j] * zs[j];
                    if (writer) {
                        out[(size_t)p * 4 + 0] = xs[j];
                        out[(size_t)p * 4 + 1] = ys[j];
                        out[(size_t)p * 4 + 2] = zs[j];
                        out[(size_t)p * 4 + 3] = 0.f;
                    }
                } else {
                    xs[j] = 0.f; ys[j] = 0.f; zs[j] = 0.f;
                    ms[j] = INFINITY;      // never selected
                }
            }
        }
        // ---- pure-VALU pair evals: 4 points x 16 receivers ----
#pragma unroll
        for (int j = 0; j < PPL; ++j) {
            const int gidx = p0 + j;
#pragma unroll
            for (int c = 0; c < RPW; ++c) {
                float cr = fmaf(rz[c], zs[j], fmaf(ry[c], ys[j], rx[c] * xs[j]));
                float d2 = fmaf(-2.0f, cr, ms[j]) + rsq[c];
                if (d2 < best[c]) { best[c] = d2; bidx[c] = gidx; }  // strict <
            }
        }
    }

    // ---- stage A: all 256 threads dump 16 packed keys to LDS ----
#pragma unroll
    for (int c = 0; c < RPW; ++c)
        lds1[tid][c] = ((unsigned long long)monotone_key(best[c]) << 32)
                       | (unsigned int)bidx[c];
    __syncthreads();

    // ---- stage B: 16 threads per receiver fold 16 sources each ----
    {
        const int c = tid & 15;
        const int g = tid >> 4;
        unsigned long long k = lds1[g * 16][c];
#pragma unroll
        for (int s = 1; s < 16; ++s) {
            unsigned long long o = lds1[g * 16 + s][c];
            if (o < k) k = o;
        }
        lds2[g][c] = k;
    }
    __syncthreads();

    // ---- stage C: final fold + one packed atomic per receiver ----
    if (tid < RPW) {
        unsigned long long k = lds2[0][tid];
#pragma unroll
        for (int p = 1; p < 16; ++p) {
            unsigned long long o = lds2[p][tid];
            if (o < k) k = o;
        }
        const int r = rq * RPW + tid;
        if (r < B) atomicMin(&ws[r], k);
    }
}

// scatter one-hot 1.0s and emit closest_points
__global__ void finalize_kernel(
        const float* __restrict__ mesh, const unsigned long long* __restrict__ ws,
        float* __restrict__ out, int L, int B) {
    const int r = threadIdx.x;
    if (r >= B) return;
    const int idx = (int)(ws[r] & 0xFFFFFFFFull);
    out[(size_t)idx * 4 + 3] = 1.0f;
    float* cp = out + (size_t)L * 4 + (size_t)r * 3;
    cp[0] = mesh[(size_t)idx * 3 + 0];
    cp[1] = mesh[(size_t)idx * 3 + 1];
    cp[2] = mesh[(size_t)idx * 3 + 2];
}

extern "C" void kernel_launch(void* const* d_in, const int* in_sizes, int n_in,
                              void* d_out, int out_size, void* d_ws, size_t ws_size,
                              hipStream_t stream) {
    const float* mesh = (const float*)d_in[0];
    const float* recv = (const float*)d_in[1];
    float* out = (float*)d_out;
    const int L = in_sizes[0] / 3;
    const int B = in_sizes[1] / 3;   // 64
    unsigned long long* ws = (unsigned long long*)d_ws;

    // init per-receiver packed (key|idx) mins to all-ones (max)
    hipMemsetAsync(ws, 0xFF, (size_t)B * sizeof(unsigned long long), stream);

    const int ntiles = (L + 1023) / 1024;
    fused_kernel<<<4 * NQ, 256, 0, stream>>>(mesh, recv, out, ws, L, B, ntiles);

    finalize_kernel<<<1, 64, 0, stream>>>(mesh, ws, out, L, B);
}